// Round 4
// baseline (605.293 us; speedup 1.0000x reference)
//
#include <hip/hip_runtime.h>
#include <stdint.h>

#define E4M3_MAX 448.0f
#define E4M3_MIN_SUB 0.001953125f   // smallest e4m3 subnormal, 2^-9

using f32x4 = __attribute__((ext_vector_type(4))) float;
using ushort8 = __attribute__((ext_vector_type(8))) unsigned short;

__device__ __forceinline__ void gload_lds16(const void* g, void* l) {
  __builtin_amdgcn_global_load_lds(
      (const __attribute__((address_space(1))) void*)g,
      (__attribute__((address_space(3))) void*)l,
      16, 0, 0);
}

// ---------------- Kernel 0: detect transport dtype of weight_fp8 ------------
// The harness may push float8_e4m3fn as f32 (flag 0), bf16 (flag 1),
// packed uint8 raw bytes (flag 2), or int32-expanded bytes (flag 3).
// Fingerprint the first 256 words: fp8-grid f32 has low 20 mantissa bits 0;
// fp8-grid bf16 halves have low 4 bits 0; int32 bytes are <=255.
// Each test passing 256/256 by accident is statistically impossible.
__global__ void detect_wfmt(const uint8_t* __restrict__ w, int* __restrict__ flag) {
  __shared__ int cnt[3];
  const int tid = threadIdx.x;
  if (tid < 3) cnt[tid] = 0;
  __syncthreads();
  const uint32_t bits = ((const uint32_t*)w)[tid];
  // f32-on-fp8-grid test
  const float fv = __uint_as_float(bits);
  const float af = fabsf(fv);
  const bool p32 = ((bits & 0xFFFFFu) == 0u) &&
                   (af == 0.f || (af >= E4M3_MIN_SUB && af <= E4M3_MAX));
  // bf16-on-fp8-grid test (both halves)
  bool pbf = true;
#pragma unroll
  for (int h = 0; h < 2; ++h) {
    const uint32_t hb = (bits >> (16 * h)) & 0xFFFFu;
    const float hv = __uint_as_float(hb << 16);
    const float ah = fabsf(hv);
    pbf = pbf && ((hb & 0xFu) == 0u) &&
          (ah == 0.f || (ah >= E4M3_MIN_SUB && ah <= E4M3_MAX));
  }
  // int32-expanded-byte test
  const bool pi = bits <= 255u;
  if (p32) atomicAdd(&cnt[0], 1);
  if (pbf) atomicAdd(&cnt[1], 1);
  if (pi) atomicAdd(&cnt[2], 1);
  __syncthreads();
  if (tid == 0) {
    int f;
    if (cnt[0] == 256) f = 0;        // f32 (test before bf16: f32 data passes bf16 test too)
    else if (cnt[1] == 256) f = 1;   // bf16
    else if (cnt[2] == 256) f = 3;   // int32 bytes
    else f = 2;                      // packed uint8
    *flag = f;
  }
}

// ---------------- Kernel 1: per-token dynamic fp8 quantization (IN-PLACE) ----
// One block per token row (K=4096). fp8 bytes overwrite the first K bytes of
// the row's own 16KB f32 region; f32 scale stored at byte offset K.
// Race-free: all reads of the row complete before the block barrier.
__global__ __launch_bounds__(256) void quant_rows(float* __restrict__ x, int K) {
  const int row = blockIdx.x;
  const int tid = threadIdx.x;
  uint8_t* xrow = (uint8_t*)(x + (size_t)row * K);

  float4 v[4];
  float am = 0.f;
#pragma unroll
  for (int p = 0; p < 4; ++p) {
    v[p] = *(const float4*)((const float*)xrow + p * 1024 + tid * 4);
    am = fmaxf(am, fmaxf(fmaxf(fabsf(v[p].x), fabsf(v[p].y)),
                         fmaxf(fabsf(v[p].z), fabsf(v[p].w))));
  }
#pragma unroll
  for (int off = 32; off > 0; off >>= 1) am = fmaxf(am, __shfl_xor(am, off));
  __shared__ float red[4];
  if ((tid & 63) == 0) red[tid >> 6] = am;
  __syncthreads();  // also orders: all row reads done before in-place writes
  am = fmaxf(fmaxf(red[0], red[1]), fmaxf(red[2], red[3]));

  const float scale = fmaxf(am / E4M3_MAX, 1e-12f);
  if (tid == 0) *(float*)(xrow + 4096) = scale;

#pragma unroll
  for (int p = 0; p < 4; ++p) {
    float q0 = fminf(fmaxf(v[p].x / scale, -E4M3_MAX), E4M3_MAX);
    float q1 = fminf(fmaxf(v[p].y / scale, -E4M3_MAX), E4M3_MAX);
    float q2 = fminf(fmaxf(v[p].z / scale, -E4M3_MAX), E4M3_MAX);
    float q3 = fminf(fmaxf(v[p].w / scale, -E4M3_MAX), E4M3_MAX);
    int pk = 0;
    pk = __builtin_amdgcn_cvt_pk_fp8_f32(q0, q1, pk, false);  // bytes 0,1 (RNE)
    pk = __builtin_amdgcn_cvt_pk_fp8_f32(q2, q3, pk, true);   // bytes 2,3
    *(int*)(xrow + p * 1024 + tid * 4) = pk;
  }
}

// ---------------- Kernel 2: normalize weights to packed fp8 (IN-PLACE) ------
// One block per weight row. Writes K fp8 bytes at the START of row n's own
// source region (stride = esize*K bytes) -> per-row regions disjoint, no
// cross-block hazard. flag 2 = already packed, no-op.
__global__ __launch_bounds__(256) void quant_w(uint8_t* __restrict__ wbase,
                                               const int* __restrict__ flag,
                                               int K) {
  const int f = *flag;
  if (f == 2) return;
  const int row = blockIdx.x;
  const int tid = threadIdx.x;

  if (f == 0) {  // f32 values on fp8 grid
    uint8_t* wrow = wbase + (size_t)row * K * 4;
    float4 v[4];
#pragma unroll
    for (int p = 0; p < 4; ++p)
      v[p] = *(const float4*)((const float*)wrow + p * 1024 + tid * 4);
    __syncthreads();
#pragma unroll
    for (int p = 0; p < 4; ++p) {
      float q0 = fminf(fmaxf(v[p].x, -E4M3_MAX), E4M3_MAX);
      float q1 = fminf(fmaxf(v[p].y, -E4M3_MAX), E4M3_MAX);
      float q2 = fminf(fmaxf(v[p].z, -E4M3_MAX), E4M3_MAX);
      float q3 = fminf(fmaxf(v[p].w, -E4M3_MAX), E4M3_MAX);
      int pk = 0;
      pk = __builtin_amdgcn_cvt_pk_fp8_f32(q0, q1, pk, false);
      pk = __builtin_amdgcn_cvt_pk_fp8_f32(q2, q3, pk, true);
      *(int*)(wrow + p * 1024 + tid * 4) = pk;
    }
  } else if (f == 1) {  // bf16 values on fp8 grid
    uint8_t* wrow = wbase + (size_t)row * K * 2;
#pragma unroll
    for (int p = 0; p < 2; ++p) {
      ushort8 h = *(const ushort8*)((const unsigned short*)wrow + p * 2048 + tid * 8);
      __syncthreads();  // executed uniformly: both p-iterations by all threads
      int pk01 = 0, pk23 = 0;
      float q[8];
#pragma unroll
      for (int j = 0; j < 8; ++j) {
        float fv = __uint_as_float(((uint32_t)h[j]) << 16);
        q[j] = fminf(fmaxf(fv, -E4M3_MAX), E4M3_MAX);
      }
      pk01 = __builtin_amdgcn_cvt_pk_fp8_f32(q[0], q[1], pk01, false);
      pk01 = __builtin_amdgcn_cvt_pk_fp8_f32(q[2], q[3], pk01, true);
      pk23 = __builtin_amdgcn_cvt_pk_fp8_f32(q[4], q[5], pk23, false);
      pk23 = __builtin_amdgcn_cvt_pk_fp8_f32(q[6], q[7], pk23, true);
      *(int*)(wrow + p * 2048 + tid * 8) = pk01;
      *(int*)(wrow + p * 2048 + tid * 8 + 4) = pk23;
    }
  } else {  // f == 3: int32-expanded bytes
    uint8_t* wrow = wbase + (size_t)row * K * 4;
    int4 v[4];
#pragma unroll
    for (int p = 0; p < 4; ++p)
      v[p] = *(const int4*)((const int*)wrow + p * 1024 + tid * 4);
    __syncthreads();
#pragma unroll
    for (int p = 0; p < 4; ++p) {
      int pk = (v[p].x & 0xFF) | ((v[p].y & 0xFF) << 8) |
               ((v[p].z & 0xFF) << 16) | ((v[p].w & 0xFF) << 24);
      *(int*)(wrow + p * 1024 + tid * 4) = pk;
    }
  }
}

// ---------------- Kernel 3: fp8 GEMM with dequant epilogue ----------------
// out[t][n] = (sum_k xq[t][k]*wq[n][k]) * in_scale[t]*w_scale[n] + bias[n]
// 128x128 tile, BK=64, 4 waves (2x2 of 64x64), m97 2-barrier structure,
// global_load_lds width-16 staging, LDS layout [ks][row][32B].
__global__ __launch_bounds__(256) void fp8_gemm(
    const uint8_t* __restrict__ Aq,      // fp8, row stride as_bytes
    const uint8_t* __restrict__ Wq,      // fp8, row stride from flag
    const int* __restrict__ wflag,
    const float* __restrict__ in_scale,  // stride ss floats per row
    const float* __restrict__ w_scale,   // [N]
    const float* __restrict__ bias,      // [N]
    float* __restrict__ out,             // [T][N] f32
    int T, int N, int K, int as_bytes, int ss) {
  __shared__ alignas(16) uint8_t As[2 * 128 * 32];  // [ks][row][32B]
  __shared__ alignas(16) uint8_t Bs[2 * 128 * 32];

  const int tid = threadIdx.x;
  const int w = tid >> 6;
  const int lane = tid & 63;

  const int wf = *wflag;
  const size_t wsb = (wf == 1) ? (size_t)K * 2 : (wf == 2 ? (size_t)K : (size_t)K * 4);

  // XCD-aware swizzle (grid = 2048, divisible by 8 -> bijective)
  const int nwg = gridDim.x;
  const int bid = blockIdx.x;
  const int cpx = nwg >> 3;
  const int wg = (bid & 7) * cpx + (bid >> 3);
  const int ntn = N >> 7;
  const int tile_n = (wg % ntn) << 7;
  const int tile_m = (wg / ntn) << 7;

  // staging: one wave covers 32 rows x 32 bytes (2 lanes/row); LDS dest is
  // linear in lane order -> matches [ks][row][32] layout.
  const int srow = w * 32 + (lane >> 1);
  const uint8_t* ga = Aq + (size_t)(tile_m + srow) * as_bytes + ((lane & 1) << 4);
  const uint8_t* gb = Wq + (size_t)(tile_n + srow) * wsb + ((lane & 1) << 4);
  uint8_t* la = As + w * 1024;
  uint8_t* lb = Bs + w * 1024;

  f32x4 acc[4][4];
#pragma unroll
  for (int i = 0; i < 4; ++i)
#pragma unroll
    for (int j = 0; j < 4; ++j) acc[i][j] = (f32x4){0.f, 0.f, 0.f, 0.f};

  const int wm = w >> 1, wn = w & 1;
  const int fr = lane & 15;   // fragment row (A) / col (B)
  const int fq = lane >> 4;   // k-offset fq*8; D-row offset fq*4
  const int a_off = (wm * 64 + fr) * 32 + fq * 8;
  const int b_off = (wn * 64 + fr) * 32 + fq * 8;

  for (int k0 = 0; k0 < K; k0 += 64) {
    gload_lds16(ga + k0, la);
    gload_lds16(ga + k0 + 32, la + 4096);
    gload_lds16(gb + k0, lb);
    gload_lds16(gb + k0 + 32, lb + 4096);
    __syncthreads();  // drains vmcnt, LDS ready
#pragma unroll
    for (int ks = 0; ks < 2; ++ks) {
      long af[4], bf[4];
#pragma unroll
      for (int mi = 0; mi < 4; ++mi)
        af[mi] = *(const long*)(As + ks * 4096 + a_off + mi * 512);
#pragma unroll
      for (int ni = 0; ni < 4; ++ni)
        bf[ni] = *(const long*)(Bs + ks * 4096 + b_off + ni * 512);
#pragma unroll
      for (int mi = 0; mi < 4; ++mi)
#pragma unroll
        for (int ni = 0; ni < 4; ++ni)
          acc[mi][ni] = __builtin_amdgcn_mfma_f32_16x16x32_fp8_fp8(
              af[mi], bf[ni], acc[mi][ni], 0, 0, 0);
    }
    __syncthreads();
  }

  // epilogue: D row = fq*4+reg, col = fr within each 16x16 fragment.
#pragma unroll
  for (int mi = 0; mi < 4; ++mi) {
    const int r0 = tile_m + wm * 64 + mi * 16 + fq * 4;
    const float s0 = in_scale[(size_t)(r0 + 0) * ss];
    const float s1 = in_scale[(size_t)(r0 + 1) * ss];
    const float s2 = in_scale[(size_t)(r0 + 2) * ss];
    const float s3 = in_scale[(size_t)(r0 + 3) * ss];
#pragma unroll
    for (int ni = 0; ni < 4; ++ni) {
      const int c = tile_n + wn * 64 + ni * 16 + fr;
      const float wsn = w_scale[c];
      const float bn = bias[c];
      float* o = out + (size_t)r0 * N + c;
      o[0]             = acc[mi][ni][0] * s0 * wsn + bn;
      o[(size_t)N]     = acc[mi][ni][1] * s1 * wsn + bn;
      o[(size_t)N * 2] = acc[mi][ni][2] * s2 * wsn + bn;
      o[(size_t)N * 3] = acc[mi][ni][3] * s3 * wsn + bn;
    }
  }
}

extern "C" void kernel_launch(void* const* d_in, const int* in_sizes, int n_in,
                              void* d_out, int out_size, void* d_ws, size_t ws_size,
                              hipStream_t stream) {
  float* x = (float*)d_in[0];           // mutated in-place (restored by harness)
  uint8_t* wq = (uint8_t*)d_in[1];      // fp8 in unknown transport dtype
  const float* wscale = (const float*)d_in[2];
  const float* bias = (const float*)d_in[3];
  float* out = (float*)d_out;
  int* flag = (int*)d_ws;               // 4 bytes of scratch for the format flag

  const int N = in_sizes[2];            // 4096 (weight_scale count)
  const int K = in_sizes[1] / N;        // 4096
  const int T = in_sizes[0] / K;        // 8192

  detect_wfmt<<<1, 256, 0, stream>>>(wq, flag);
  quant_rows<<<T, 256, 0, stream>>>(x, K);
  quant_w<<<N, 256, 0, stream>>>(wq, flag, K);

  const uint8_t* xq = (const uint8_t*)x;  // row stride K*4 bytes
  const float* in_scale = x + K / 4;      // scale at float offset 1024, stride K
  const int grid = (T / 128) * (N / 128);
  fp8_gemm<<<grid, 256, 0, stream>>>(xq, wq, flag, in_scale, wscale, bias, out,
                                     T, N, K, K * 4, K);
}

// Round 5
// 529.479 us; speedup vs baseline: 1.1432x; 1.1432x over previous
//
#include <hip/hip_runtime.h>
#include <stdint.h>

#define E4M3_MAX 448.0f
#define E4M3_MIN_SUB 0.001953125f   // smallest e4m3 subnormal, 2^-9

using f32x4 = __attribute__((ext_vector_type(4))) float;
using ushort8 = __attribute__((ext_vector_type(8))) unsigned short;

__device__ __forceinline__ void gload_lds16(const void* g, void* l) {
  __builtin_amdgcn_global_load_lds(
      (const __attribute__((address_space(1))) void*)g,
      (__attribute__((address_space(3))) void*)l,
      16, 0, 0);
}

// ---------------- Kernel 0: detect transport dtype of weight_fp8 ------------
// flag 0 = f32-on-fp8-grid, 1 = bf16, 2 = packed uint8, 3 = int32 bytes.
__global__ void detect_wfmt(const uint8_t* __restrict__ w, int* __restrict__ flag) {
  __shared__ int cnt[3];
  const int tid = threadIdx.x;
  if (tid < 3) cnt[tid] = 0;
  __syncthreads();
  const uint32_t bits = ((const uint32_t*)w)[tid];
  const float fv = __uint_as_float(bits);
  const float af = fabsf(fv);
  const bool p32 = ((bits & 0xFFFFFu) == 0u) &&
                   (af == 0.f || (af >= E4M3_MIN_SUB && af <= E4M3_MAX));
  bool pbf = true;
#pragma unroll
  for (int h = 0; h < 2; ++h) {
    const uint32_t hb = (bits >> (16 * h)) & 0xFFFFu;
    const float hv = __uint_as_float(hb << 16);
    const float ah = fabsf(hv);
    pbf = pbf && ((hb & 0xFu) == 0u) &&
          (ah == 0.f || (ah >= E4M3_MIN_SUB && ah <= E4M3_MAX));
  }
  const bool pi = bits <= 255u;
  if (p32) atomicAdd(&cnt[0], 1);
  if (pbf) atomicAdd(&cnt[1], 1);
  if (pi) atomicAdd(&cnt[2], 1);
  __syncthreads();
  if (tid == 0) {
    int f;
    if (cnt[0] == 256) f = 0;
    else if (cnt[1] == 256) f = 1;
    else if (cnt[2] == 256) f = 3;
    else f = 2;
    *flag = f;
  }
}

// ---------------- Kernel 1: per-token dynamic fp8 quantization (IN-PLACE) ----
__global__ __launch_bounds__(256) void quant_rows(float* __restrict__ x, int K) {
  const int row = blockIdx.x;
  const int tid = threadIdx.x;
  uint8_t* xrow = (uint8_t*)(x + (size_t)row * K);

  float4 v[4];
  float am = 0.f;
#pragma unroll
  for (int p = 0; p < 4; ++p) {
    v[p] = *(const float4*)((const float*)xrow + p * 1024 + tid * 4);
    am = fmaxf(am, fmaxf(fmaxf(fabsf(v[p].x), fabsf(v[p].y)),
                         fmaxf(fabsf(v[p].z), fabsf(v[p].w))));
  }
#pragma unroll
  for (int off = 32; off > 0; off >>= 1) am = fmaxf(am, __shfl_xor(am, off));
  __shared__ float red[4];
  if ((tid & 63) == 0) red[tid >> 6] = am;
  __syncthreads();  // also orders: all row reads done before in-place writes
  am = fmaxf(fmaxf(red[0], red[1]), fmaxf(red[2], red[3]));

  const float scale = fmaxf(am / E4M3_MAX, 1e-12f);
  if (tid == 0) *(float*)(xrow + 4096) = scale;

#pragma unroll
  for (int p = 0; p < 4; ++p) {
    float q0 = fminf(fmaxf(v[p].x / scale, -E4M3_MAX), E4M3_MAX);
    float q1 = fminf(fmaxf(v[p].y / scale, -E4M3_MAX), E4M3_MAX);
    float q2 = fminf(fmaxf(v[p].z / scale, -E4M3_MAX), E4M3_MAX);
    float q3 = fminf(fmaxf(v[p].w / scale, -E4M3_MAX), E4M3_MAX);
    int pk = 0;
    pk = __builtin_amdgcn_cvt_pk_fp8_f32(q0, q1, pk, false);
    pk = __builtin_amdgcn_cvt_pk_fp8_f32(q2, q3, pk, true);
    *(int*)(xrow + p * 1024 + tid * 4) = pk;
  }
}

// ---------------- Kernel 2: normalize weights to packed fp8 (IN-PLACE) ------
__global__ __launch_bounds__(256) void quant_w(uint8_t* __restrict__ wbase,
                                               const int* __restrict__ flag,
                                               int K) {
  const int f = *flag;
  if (f == 2) return;
  const int row = blockIdx.x;
  const int tid = threadIdx.x;

  if (f == 0) {
    uint8_t* wrow = wbase + (size_t)row * K * 4;
    float4 v[4];
#pragma unroll
    for (int p = 0; p < 4; ++p)
      v[p] = *(const float4*)((const float*)wrow + p * 1024 + tid * 4);
    __syncthreads();
#pragma unroll
    for (int p = 0; p < 4; ++p) {
      float q0 = fminf(fmaxf(v[p].x, -E4M3_MAX), E4M3_MAX);
      float q1 = fminf(fmaxf(v[p].y, -E4M3_MAX), E4M3_MAX);
      float q2 = fminf(fmaxf(v[p].z, -E4M3_MAX), E4M3_MAX);
      float q3 = fminf(fmaxf(v[p].w, -E4M3_MAX), E4M3_MAX);
      int pk = 0;
      pk = __builtin_amdgcn_cvt_pk_fp8_f32(q0, q1, pk, false);
      pk = __builtin_amdgcn_cvt_pk_fp8_f32(q2, q3, pk, true);
      *(int*)(wrow + p * 1024 + tid * 4) = pk;
    }
  } else if (f == 1) {
    uint8_t* wrow = wbase + (size_t)row * K * 2;
#pragma unroll
    for (int p = 0; p < 2; ++p) {
      ushort8 h = *(const ushort8*)((const unsigned short*)wrow + p * 2048 + tid * 8);
      __syncthreads();
      int pk01 = 0, pk23 = 0;
      float q[8];
#pragma unroll
      for (int j = 0; j < 8; ++j) {
        float fv = __uint_as_float(((uint32_t)h[j]) << 16);
        q[j] = fminf(fmaxf(fv, -E4M3_MAX), E4M3_MAX);
      }
      pk01 = __builtin_amdgcn_cvt_pk_fp8_f32(q[0], q[1], pk01, false);
      pk01 = __builtin_amdgcn_cvt_pk_fp8_f32(q[2], q[3], pk01, true);
      pk23 = __builtin_amdgcn_cvt_pk_fp8_f32(q[4], q[5], pk23, false);
      pk23 = __builtin_amdgcn_cvt_pk_fp8_f32(q[6], q[7], pk23, true);
      *(int*)(wrow + p * 2048 + tid * 8) = pk01;
      *(int*)(wrow + p * 2048 + tid * 8 + 4) = pk23;
    }
  } else {
    uint8_t* wrow = wbase + (size_t)row * K * 4;
    int4 v[4];
#pragma unroll
    for (int p = 0; p < 4; ++p)
      v[p] = *(const int4*)((const int*)wrow + p * 1024 + tid * 4);
    __syncthreads();
#pragma unroll
    for (int p = 0; p < 4; ++p) {
      int pk = (v[p].x & 0xFF) | ((v[p].y & 0xFF) << 8) |
               ((v[p].z & 0xFF) << 16) | ((v[p].w & 0xFF) << 24);
      *(int*)(wrow + p * 1024 + tid * 4) = pk;
    }
  }
}

// ---------------- Kernel 3: fp8 GEMM, 256x256 tile, 4-phase/K-tile ----------
// 8 waves (2M x 4N), per-wave output 128x64 (8 M-frags x 4 N-frags x ks=2).
// 3-buffer LDS, 2-tile-ahead prefetch (1 gload16/phase), counted vmcnt(4) at
// tile end only (never 0 mid-loop), raw s_barrier, setprio around MFMA.
// LDS per buf: [A/B][ks][row*32+b] (row-major 32B rows, k-outer).
__global__ __launch_bounds__(512, 2) void fp8_gemm(
    const uint8_t* __restrict__ Aq,      // fp8, row stride as_bytes
    const uint8_t* __restrict__ Wq,      // fp8, row stride from flag
    const int* __restrict__ wflag,
    const float* __restrict__ in_scale,  // stride ss floats per row
    const float* __restrict__ w_scale,   // [N]
    const float* __restrict__ bias,      // [N]
    float* __restrict__ out,             // [T][N] f32
    int T, int N, int K, int as_bytes, int ss) {
  __shared__ alignas(16) uint8_t S[3][2][2][8192];  // [buf][A/B][ks][row*32+b] = 96KB

  const int tid = threadIdx.x;
  const int w = tid >> 6;
  const int lane = tid & 63;

  const int wf = *wflag;
  const size_t wsb = (wf == 1) ? (size_t)K * 2 : (wf == 2 ? (size_t)K : (size_t)K * 4);

  // XCD-aware swizzle: grid = (T/256)*(N/256) = 512, divisible by 8 -> bijective
  const int nwg = gridDim.x;
  const int bid = blockIdx.x;
  const int cpx = nwg >> 3;
  const int wg = (bid & 7) * cpx + (bid >> 3);
  const int ntn = N >> 8;
  const int tile_n = (wg % ntn) << 8;
  const int tile_m = (wg / ntn) << 8;

  // staging: thread t covers row t>>1 of the 256-row tile, 16B half (t&1).
  // LDS dest linear in lane order: wave w base + lane*16 == granule index t.
  const int srow = tid >> 1;
  const int sbyte = (tid & 1) << 4;
  const uint8_t* gA = Aq + (size_t)(tile_m + srow) * as_bytes + sbyte;
  const uint8_t* gB = Wq + (size_t)(tile_n + srow) * wsb + sbyte;

  const int wm = w >> 2, wn = w & 3;      // 2 x 4 wave grid
  const int fr = lane & 15, fq = lane >> 4;
  const int aoff = (wm * 128 + fr) * 32 + fq * 8;  // + mi*512
  const int boff = (wn * 64 + fr) * 32 + fq * 8;   // + ni*512

  f32x4 acc[8][4];
#pragma unroll
  for (int i = 0; i < 8; ++i)
#pragma unroll
    for (int j = 0; j < 4; ++j) acc[i][j] = (f32x4){0.f, 0.f, 0.f, 0.f};

#define STAGE(buf_, M_, ks_, k0_)                                        \
  gload_lds16((M_ ? gB : gA) + (k0_) + (ks_) * 32,                       \
              &S[(buf_)][(M_)][(ks_)][w * 1024])

  const int NT = K >> 6;  // K-tiles of 64

  // prologue: stage tiles 0 and 1
#pragma unroll
  for (int p = 0; p < 4; ++p) STAGE(0, (p >> 1), (p & 1), 0);
#pragma unroll
  for (int p = 0; p < 4; ++p) STAGE(1, (p >> 1), (p & 1), 64);
  asm volatile("s_waitcnt vmcnt(4)" ::: "memory");  // tile 0 resident
  __builtin_amdgcn_sched_barrier(0);
  __builtin_amdgcn_s_barrier();

  int buf = 0;
  for (int kt = 0; kt < NT; ++kt) {
    const int sbuf = (buf >= 1) ? buf - 1 : buf + 2;  // (kt+2) % 3
    const int k2 = (kt + 2) << 6;
    const bool pf = (kt + 2) < NT;
    long bfr[4][2];
#pragma unroll
    for (int qd = 0; qd < 4; ++qd) {
      long afr[2][2];
      // ds_read this quadrant's A-frags (and all B-frags on phase 0)
#pragma unroll
      for (int m2 = 0; m2 < 2; ++m2)
#pragma unroll
        for (int ks = 0; ks < 2; ++ks)
          afr[m2][ks] = *(const long*)&S[buf][0][ks][aoff + (qd * 2 + m2) * 512];
      if (qd == 0) {
#pragma unroll
        for (int ni = 0; ni < 4; ++ni)
#pragma unroll
          for (int ks = 0; ks < 2; ++ks)
            bfr[ni][ks] = *(const long*)&S[buf][1][ks][boff + ni * 512];
      }
      // stage one issue of tile kt+2 (spread: 1 gload16 per phase)
      if (pf) {
        if (qd == 0) STAGE(sbuf, 0, 0, k2);
        else if (qd == 1) STAGE(sbuf, 0, 1, k2);
        else if (qd == 2) STAGE(sbuf, 1, 0, k2);
        else STAGE(sbuf, 1, 1, k2);
      }
      __builtin_amdgcn_s_barrier();
      __builtin_amdgcn_s_setprio(1);
#pragma unroll
      for (int ks = 0; ks < 2; ++ks)
#pragma unroll
        for (int m2 = 0; m2 < 2; ++m2)
#pragma unroll
          for (int ni = 0; ni < 4; ++ni)
            acc[qd * 2 + m2][ni] = __builtin_amdgcn_mfma_f32_16x16x32_fp8_fp8(
                afr[m2][ks], bfr[ni][ks], acc[qd * 2 + m2][ni], 0, 0, 0);
      __builtin_amdgcn_s_setprio(0);
      if (qd == 3) {
        // counted gate: next tile's 4 loads done; kt+2's 4 may stay in flight
        if (pf) asm volatile("s_waitcnt vmcnt(4)" ::: "memory");
        else    asm volatile("s_waitcnt vmcnt(0)" ::: "memory");
        __builtin_amdgcn_sched_barrier(0);
      }
      __builtin_amdgcn_s_barrier();
    }
    buf = (buf == 2) ? 0 : buf + 1;
  }
#undef STAGE

  // epilogue: D row = fq*4+reg, col = fr within each 16x16 fragment.
#pragma unroll
  for (int mi = 0; mi < 8; ++mi) {
    const int r0 = tile_m + wm * 128 + mi * 16 + fq * 4;
    const float s0 = in_scale[(size_t)(r0 + 0) * ss];
    const float s1 = in_scale[(size_t)(r0 + 1) * ss];
    const float s2 = in_scale[(size_t)(r0 + 2) * ss];
    const float s3 = in_scale[(size_t)(r0 + 3) * ss];
#pragma unroll
    for (int ni = 0; ni < 4; ++ni) {
      const int c = tile_n + wn * 64 + ni * 16 + fr;
      const float wsn = w_scale[c];
      const float bn = bias[c];
      float* o = out + (size_t)r0 * N + c;
      o[0]             = acc[mi][ni][0] * s0 * wsn + bn;
      o[(size_t)N]     = acc[mi][ni][1] * s1 * wsn + bn;
      o[(size_t)N * 2] = acc[mi][ni][2] * s2 * wsn + bn;
      o[(size_t)N * 3] = acc[mi][ni][3] * s3 * wsn + bn;
    }
  }
}

extern "C" void kernel_launch(void* const* d_in, const int* in_sizes, int n_in,
                              void* d_out, int out_size, void* d_ws, size_t ws_size,
                              hipStream_t stream) {
  float* x = (float*)d_in[0];           // mutated in-place (restored by harness)
  uint8_t* wq = (uint8_t*)d_in[1];      // fp8 in unknown transport dtype
  const float* wscale = (const float*)d_in[2];
  const float* bias = (const float*)d_in[3];
  float* out = (float*)d_out;
  int* flag = (int*)d_ws;

  const int N = in_sizes[2];            // 4096
  const int K = in_sizes[1] / N;        // 4096
  const int T = in_sizes[0] / K;        // 8192

  detect_wfmt<<<1, 256, 0, stream>>>(wq, flag);
  quant_rows<<<T, 256, 0, stream>>>(x, K);
  quant_w<<<N, 256, 0, stream>>>(wq, flag, K);

  const uint8_t* xq = (const uint8_t*)x;  // row stride K*4 bytes
  const float* in_scale = x + K / 4;      // scale at float offset 1024, stride K
  const int grid = (T / 256) * (N / 256); // 512
  fp8_gemm<<<grid, 512, 0, stream>>>(xq, wq, flag, in_scale, wscale, bias, out,
                                     T, N, K, K * 4, K);
}

// Round 7
// 498.567 us; speedup vs baseline: 1.2141x; 1.0620x over previous
//
#include <hip/hip_runtime.h>
#include <stdint.h>

#define E4M3_MAX 448.0f
#define E4M3_MIN_SUB 0.001953125f   // smallest e4m3 subnormal, 2^-9

using f32x4 = __attribute__((ext_vector_type(4))) float;
using ushort8 = __attribute__((ext_vector_type(8))) unsigned short;

__device__ __forceinline__ void gload_lds16(const void* g, void* l) {
  __builtin_amdgcn_global_load_lds(
      (const __attribute__((address_space(1))) void*)g,
      (__attribute__((address_space(3))) void*)l,
      16, 0, 0);
}

// ---------------- Kernel 0: detect transport dtype of weight_fp8 ------------
// flag 0 = f32-on-fp8-grid, 1 = bf16, 2 = packed uint8, 3 = int32 bytes.
__global__ void detect_wfmt(const uint8_t* __restrict__ w, int* __restrict__ flag) {
  __shared__ int cnt[3];
  const int tid = threadIdx.x;
  if (tid < 3) cnt[tid] = 0;
  __syncthreads();
  const uint32_t bits = ((const uint32_t*)w)[tid];
  const float fv = __uint_as_float(bits);
  const float af = fabsf(fv);
  const bool p32 = ((bits & 0xFFFFFu) == 0u) &&
                   (af == 0.f || (af >= E4M3_MIN_SUB && af <= E4M3_MAX));
  bool pbf = true;
#pragma unroll
  for (int h = 0; h < 2; ++h) {
    const uint32_t hb = (bits >> (16 * h)) & 0xFFFFu;
    const float hv = __uint_as_float(hb << 16);
    const float ah = fabsf(hv);
    pbf = pbf && ((hb & 0xFu) == 0u) &&
          (ah == 0.f || (ah >= E4M3_MIN_SUB && ah <= E4M3_MAX));
  }
  const bool pi = bits <= 255u;
  if (p32) atomicAdd(&cnt[0], 1);
  if (pbf) atomicAdd(&cnt[1], 1);
  if (pi) atomicAdd(&cnt[2], 1);
  __syncthreads();
  if (tid == 0) {
    int f;
    if (cnt[0] == 256) f = 0;
    else if (cnt[1] == 256) f = 1;
    else if (cnt[2] == 256) f = 3;
    else f = 2;
    *flag = f;
  }
}

// ---------------- Kernel 1: per-token dynamic fp8 quantization (IN-PLACE) ----
// fp8 bytes at [r*16K, r*16K+4K), f32 scale at r*16K+4096. Bytes [8K,16K) of
// each row slot stay free for the A-planes (repack_A).
__global__ __launch_bounds__(256) void quant_rows(float* __restrict__ x, int K) {
  const int row = blockIdx.x;
  const int tid = threadIdx.x;
  uint8_t* xrow = (uint8_t*)(x + (size_t)row * K);

  float4 v[4];
  float am = 0.f;
#pragma unroll
  for (int p = 0; p < 4; ++p) {
    v[p] = *(const float4*)((const float*)xrow + p * 1024 + tid * 4);
    am = fmaxf(am, fmaxf(fmaxf(fabsf(v[p].x), fabsf(v[p].y)),
                         fmaxf(fabsf(v[p].z), fabsf(v[p].w))));
  }
#pragma unroll
  for (int off = 32; off > 0; off >>= 1) am = fmaxf(am, __shfl_xor(am, off));
  __shared__ float red[4];
  if ((tid & 63) == 0) red[tid >> 6] = am;
  __syncthreads();  // also orders: all row reads done before in-place writes
  am = fmaxf(fmaxf(red[0], red[1]), fmaxf(red[2], red[3]));

  const float scale = fmaxf(am / E4M3_MAX, 1e-12f);  // exact, matches reference
  const float rin = 1.0f / scale;                    // per-element multiply below
  if (tid == 0) *(float*)(xrow + 4096) = scale;

#pragma unroll
  for (int p = 0; p < 4; ++p) {
    float q0 = fminf(fmaxf(v[p].x * rin, -E4M3_MAX), E4M3_MAX);
    float q1 = fminf(fmaxf(v[p].y * rin, -E4M3_MAX), E4M3_MAX);
    float q2 = fminf(fmaxf(v[p].z * rin, -E4M3_MAX), E4M3_MAX);
    float q3 = fminf(fmaxf(v[p].w * rin, -E4M3_MAX), E4M3_MAX);
    int pk = 0;
    pk = __builtin_amdgcn_cvt_pk_fp8_f32(q0, q1, pk, false);
    pk = __builtin_amdgcn_cvt_pk_fp8_f32(q2, q3, pk, true);
    *(int*)(xrow + p * 1024 + tid * 4) = pk;
  }
}

// ---------------- Kernel 2: normalize weights to packed fp8 (IN-PLACE) ------
__global__ __launch_bounds__(256) void quant_w(uint8_t* __restrict__ wbase,
                                               const int* __restrict__ flag,
                                               int K) {
  const int f = *flag;
  if (f == 2) return;
  const int row = blockIdx.x;
  const int tid = threadIdx.x;

  if (f == 0) {
    uint8_t* wrow = wbase + (size_t)row * K * 4;
    float4 v[4];
#pragma unroll
    for (int p = 0; p < 4; ++p)
      v[p] = *(const float4*)((const float*)wrow + p * 1024 + tid * 4);
    __syncthreads();
#pragma unroll
    for (int p = 0; p < 4; ++p) {
      float q0 = fminf(fmaxf(v[p].x, -E4M3_MAX), E4M3_MAX);
      float q1 = fminf(fmaxf(v[p].y, -E4M3_MAX), E4M3_MAX);
      float q2 = fminf(fmaxf(v[p].z, -E4M3_MAX), E4M3_MAX);
      float q3 = fminf(fmaxf(v[p].w, -E4M3_MAX), E4M3_MAX);
      int pk = 0;
      pk = __builtin_amdgcn_cvt_pk_fp8_f32(q0, q1, pk, false);
      pk = __builtin_amdgcn_cvt_pk_fp8_f32(q2, q3, pk, true);
      *(int*)(wrow + p * 1024 + tid * 4) = pk;
    }
  } else if (f == 1) {
    uint8_t* wrow = wbase + (size_t)row * K * 2;
#pragma unroll
    for (int p = 0; p < 2; ++p) {
      ushort8 h = *(const ushort8*)((const unsigned short*)wrow + p * 2048 + tid * 8);
      __syncthreads();
      int pk01 = 0, pk23 = 0;
      float q[8];
#pragma unroll
      for (int j = 0; j < 8; ++j) {
        float fv = __uint_as_float(((uint32_t)h[j]) << 16);
        q[j] = fminf(fmaxf(fv, -E4M3_MAX), E4M3_MAX);
      }
      pk01 = __builtin_amdgcn_cvt_pk_fp8_f32(q[0], q[1], pk01, false);
      pk01 = __builtin_amdgcn_cvt_pk_fp8_f32(q[2], q[3], pk01, true);
      pk23 = __builtin_amdgcn_cvt_pk_fp8_f32(q[4], q[5], pk23, false);
      pk23 = __builtin_amdgcn_cvt_pk_fp8_f32(q[6], q[7], pk23, true);
      *(int*)(wrow + p * 2048 + tid * 8) = pk01;
      *(int*)(wrow + p * 2048 + tid * 8 + 4) = pk23;
    }
  } else {
    uint8_t* wrow = wbase + (size_t)row * K * 4;
    int4 v[4];
#pragma unroll
    for (int p = 0; p < 4; ++p)
      v[p] = *(const int4*)((const int*)wrow + p * 1024 + tid * 4);
    __syncthreads();
#pragma unroll
    for (int p = 0; p < 4; ++p) {
      int pk = (v[p].x & 0xFF) | ((v[p].y & 0xFF) << 8) |
               ((v[p].z & 0xFF) << 16) | ((v[p].w & 0xFF) << 24);
      *(int*)(wrow + p * 1024 + tid * 4) = pk;
    }
  }
}

// ---------------- Kernel 2b: repack A into conflict-free planes -------------
// Plane p = (g, kt): 16KB = [ks 2][fq 4][row 256][8B], placed in the FREE
// second half of row-slots 2p, 2p+1: section ks at (2p+ks)*16384 + 8192.
// Disjoint from fp8 data (<4100) by construction; pass-separated from quant.
__global__ __launch_bounds__(256) void repack_A(uint8_t* __restrict__ xb, int K) {
  const int nkt = K >> 6;
  const int g = blockIdx.x / nkt;
  const int kt = blockIdx.x % nkt;
  const int lr = threadIdx.x;
  const size_t rowb = (size_t)K * 4;
  const uint8_t* s = xb + (size_t)(g * 256 + lr) * rowb + kt * 64;
  uint4 d0 = *(const uint4*)(s);
  uint4 d1 = *(const uint4*)(s + 16);
  uint4 d2 = *(const uint4*)(s + 32);
  uint4 d3 = *(const uint4*)(s + 48);
  uint2 pc[8] = {{d0.x, d0.y}, {d0.z, d0.w}, {d1.x, d1.y}, {d1.z, d1.w},
                 {d2.x, d2.y}, {d2.z, d2.w}, {d3.x, d3.y}, {d3.z, d3.w}};
  const size_t p = (size_t)g * nkt + kt;
#pragma unroll
  for (int pi = 0; pi < 8; ++pi)
    *(uint2*)(xb + (2 * p + (pi >> 2)) * 16384 + 8192 + (pi & 3) * 2048 + lr * 8) = pc[pi];
}

// ---------------- Kernel 2c: repack W into planes (flag 0/1/3) --------------
// flag 0/3 (4B rows): like repack_A. flag 1 (2B rows): plane split into four
// 4KB chunks at (4p+c)*8192 + 4096. flag 2: no free space -> GEMM uses the
// old row-major path for B (dead in practice; flag==0 confirmed).
__global__ __launch_bounds__(256) void repack_W(uint8_t* __restrict__ wb,
                                                const int* __restrict__ flag,
                                                int K) {
  const int f = *flag;
  if (f == 2) return;
  const int nkt = K >> 6;
  const int g = blockIdx.x / nkt;
  const int kt = blockIdx.x % nkt;
  const int lr = threadIdx.x;
  const size_t rowb = (f == 1) ? (size_t)K * 2 : (size_t)K * 4;
  const uint8_t* s = wb + (size_t)(g * 256 + lr) * rowb + kt * 64;
  uint4 d0 = *(const uint4*)(s);
  uint4 d1 = *(const uint4*)(s + 16);
  uint4 d2 = *(const uint4*)(s + 32);
  uint4 d3 = *(const uint4*)(s + 48);
  uint2 pc[8] = {{d0.x, d0.y}, {d0.z, d0.w}, {d1.x, d1.y}, {d1.z, d1.w},
                 {d2.x, d2.y}, {d2.z, d2.w}, {d3.x, d3.y}, {d3.z, d3.w}};
  const size_t p = (size_t)g * nkt + kt;
#pragma unroll
  for (int pi = 0; pi < 8; ++pi) {
    const int pb = (pi >> 2) * 8192 + (pi & 3) * 2048 + lr * 8;  // plane byte
    uint8_t* d;
    if (f == 1) d = wb + (4 * p + (pb >> 12)) * 8192 + 4096 + (pb & 4095);
    else        d = wb + (2 * p + (pi >> 2)) * 16384 + 8192 + (pb & 8191);
    *(uint2*)d = pc[pi];
  }
}

// ---------------- Kernel 3: fp8 GEMM, 256x256 tile, 4-phase/K-tile ----------
// 8 waves (2M x 4N), 3-buffer LDS, 2-tile-ahead prefetch (1 gload16/phase),
// counted vmcnt(4) at tile end, raw s_barrier, setprio around MFMA.
// LDS image per (buf, A/B, ks) = the 8KB plane section [fq 4][row 256][8B]:
// fragment reads are 8B-stride contiguous per 16-lane quarter -> conflict-free.
__global__ __launch_bounds__(512, 2) void fp8_gemm(
    const uint8_t* __restrict__ Aq,      // x buffer (fp8 + scales + A-planes)
    const uint8_t* __restrict__ Wq,      // W buffer (fp8 + W-planes)
    const int* __restrict__ wflag,
    const float* __restrict__ in_scale,  // stride ss floats per row
    const float* __restrict__ w_scale,   // [N]
    const float* __restrict__ bias,      // [N]
    float* __restrict__ out,             // [T][N] f32
    int T, int N, int K, int ss) {
  __shared__ alignas(16) uint8_t S[3][2][2][8192];  // [buf][A/B][ks][plane 8KB]

  const int tid = threadIdx.x;
  const int w = tid >> 6;
  const int lane = tid & 63;
  const int wf = *wflag;
  const int nkt = K >> 6;

  // XCD-aware swizzle: grid = 512, divisible by 8 -> bijective
  const int nwg = gridDim.x;
  const int bid = blockIdx.x;
  const int cpx = nwg >> 3;
  const int wg = (bid & 7) * cpx + (bid >> 3);
  const int ntn = N >> 8;
  const int tile_n = (wg % ntn) << 8;
  const int tile_m = (wg / ntn) << 8;
  const int gm = tile_m >> 8, gn = tile_n >> 8;

  // staging source bases (thread t reads plane byte t*16; LDS dest linear)
  const uint8_t* aS = Aq + (size_t)2 * gm * nkt * 16384 + 8192 + tid * 16;
  const uint8_t* bS0 = Wq + (size_t)2 * gn * nkt * 16384 + 8192 + tid * 16;          // wf 0/3
  const uint8_t* bS1 = Wq + ((size_t)4 * gn * nkt + (tid >> 8)) * 8192 + 4096 +
                       ((tid * 16) & 4095);                                          // wf 1
  const uint8_t* bS2 = Wq + (size_t)(tile_n + (tid >> 1)) * K + ((tid & 1) << 4);    // wf 2

  const int wm = w >> 2, wn = w & 3;      // 2 x 4 wave grid
  const int fr = lane & 15, fq = lane >> 4;
  const int a_base = fq * 2048 + (wm * 128 + fr) * 8;                 // + mi*128
  const int b_base = (wf == 2) ? ((wn * 64 + fr) * 32 + fq * 8)       // old layout
                               : (fq * 2048 + (wn * 64 + fr) * 8);
  const int b_step = (wf == 2) ? 512 : 128;

  f32x4 acc[8][4];
#pragma unroll
  for (int i = 0; i < 8; ++i)
#pragma unroll
    for (int j = 0; j < 4; ++j) acc[i][j] = (f32x4){0.f, 0.f, 0.f, 0.f};

#define STAGE_A(buf_, ks_, kt_)                                              \
  gload_lds16(aS + (size_t)(2 * (kt_) + (ks_)) * 16384, &S[(buf_)][0][(ks_)][w * 1024])
#define STAGE_B(buf_, ks_, kt_)                                              \
  gload_lds16((wf == 2) ? (bS2 + (kt_) * 64 + (ks_) * 32)                    \
              : (wf == 1) ? (bS1 + (size_t)(4 * (kt_) + 2 * (ks_)) * 8192)   \
                          : (bS0 + (size_t)(2 * (kt_) + (ks_)) * 16384),     \
              &S[(buf_)][1][(ks_)][w * 1024])

  const int NT = nkt;
  // prologue: stage tiles 0 and 1 (4 issues each: A0,A1,B0,B1)
  STAGE_A(0, 0, 0); STAGE_A(0, 1, 0); STAGE_B(0, 0, 0); STAGE_B(0, 1, 0);
  STAGE_A(1, 0, 1); STAGE_A(1, 1, 1); STAGE_B(1, 0, 1); STAGE_B(1, 1, 1);
  asm volatile("s_waitcnt vmcnt(4)" ::: "memory");  // tile 0 resident
  __builtin_amdgcn_sched_barrier(0);
  __builtin_amdgcn_s_barrier();

  int buf = 0;
  for (int kt = 0; kt < NT; ++kt) {
    const int sbuf = (buf >= 1) ? buf - 1 : buf + 2;  // (kt+2) % 3
    const int k2 = kt + 2;
    const bool pf = k2 < NT;
    long bfr[4][2];
#pragma unroll
    for (int qd = 0; qd < 4; ++qd) {
      long afr[2][2];
#pragma unroll
      for (int m2 = 0; m2 < 2; ++m2)
#pragma unroll
        for (int ks = 0; ks < 2; ++ks)
          afr[m2][ks] = *(const long*)&S[buf][0][ks][a_base + (qd * 2 + m2) * 128];
      if (qd == 0) {
#pragma unroll
        for (int ni = 0; ni < 4; ++ni)
#pragma unroll
          for (int ks = 0; ks < 2; ++ks)
            bfr[ni][ks] = *(const long*)&S[buf][1][ks][b_base + ni * b_step];
      }
      if (pf) {
        if (qd == 0) STAGE_A(sbuf, 0, k2);
        else if (qd == 1) STAGE_A(sbuf, 1, k2);
        else if (qd == 2) STAGE_B(sbuf, 0, k2);
        else STAGE_B(sbuf, 1, k2);
      }
      __builtin_amdgcn_s_barrier();
      __builtin_amdgcn_s_setprio(1);
#pragma unroll
      for (int ks = 0; ks < 2; ++ks)
#pragma unroll
        for (int m2 = 0; m2 < 2; ++m2)
#pragma unroll
          for (int ni = 0; ni < 4; ++ni)
            acc[qd * 2 + m2][ni] = __builtin_amdgcn_mfma_f32_16x16x32_fp8_fp8(
                afr[m2][ks], bfr[ni][ks], acc[qd * 2 + m2][ni], 0, 0, 0);
      __builtin_amdgcn_s_setprio(0);
      if (qd == 3) {
        if (pf) asm volatile("s_waitcnt vmcnt(4)" ::: "memory");
        else    asm volatile("s_waitcnt vmcnt(0)" ::: "memory");
        __builtin_amdgcn_sched_barrier(0);
      }
      __builtin_amdgcn_s_barrier();
    }
    buf = (buf == 2) ? 0 : buf + 1;
  }
#undef STAGE_A
#undef STAGE_B

  // epilogue: D row = fq*4+reg, col = fr within each 16x16 fragment.
#pragma unroll
  for (int mi = 0; mi < 8; ++mi) {
    const int r0 = tile_m + wm * 128 + mi * 16 + fq * 4;
    const float s0 = in_scale[(size_t)(r0 + 0) * ss];
    const float s1 = in_scale[(size_t)(r0 + 1) * ss];
    const float s2 = in_scale[(size_t)(r0 + 2) * ss];
    const float s3 = in_scale[(size_t)(r0 + 3) * ss];
#pragma unroll
    for (int ni = 0; ni < 4; ++ni) {
      const int c = tile_n + wn * 64 + ni * 16 + fr;
      const float wsn = w_scale[c];
      const float bn = bias[c];
      float* o = out + (size_t)r0 * N + c;
      o[0]             = acc[mi][ni][0] * s0 * wsn + bn;
      o[(size_t)N]     = acc[mi][ni][1] * s1 * wsn + bn;
      o[(size_t)N * 2] = acc[mi][ni][2] * s2 * wsn + bn;
      o[(size_t)N * 3] = acc[mi][ni][3] * s3 * wsn + bn;
    }
  }
}

extern "C" void kernel_launch(void* const* d_in, const int* in_sizes, int n_in,
                              void* d_out, int out_size, void* d_ws, size_t ws_size,
                              hipStream_t stream) {
  float* x = (float*)d_in[0];           // mutated in-place (restored by harness)
  uint8_t* wq = (uint8_t*)d_in[1];      // fp8 in unknown transport dtype
  const float* wscale = (const float*)d_in[2];
  const float* bias = (const float*)d_in[3];
  float* out = (float*)d_out;
  int* flag = (int*)d_ws;

  const int N = in_sizes[2];            // 4096
  const int K = in_sizes[1] / N;        // 4096
  const int T = in_sizes[0] / K;        // 8192

  detect_wfmt<<<1, 256, 0, stream>>>(wq, flag);
  quant_rows<<<T, 256, 0, stream>>>(x, K);
  quant_w<<<N, 256, 0, stream>>>(wq, flag, K);
  repack_A<<<(T / 256) * (K / 64), 256, 0, stream>>>((uint8_t*)x, K);
  repack_W<<<(N / 256) * (K / 64), 256, 0, stream>>>(wq, flag, K);

  const float* in_scale = x + K / 4;      // scale at float offset 1024, stride K
  const int grid = (T / 256) * (N / 256); // 512
  fp8_gemm<<<grid, 512, 0, stream>>>((const uint8_t*)x, wq, flag, in_scale,
                                     wscale, bias, out, T, N, K, K);
}